// Round 7
// baseline (3654.498 us; speedup 1.0000x reference)
//
#include <hip/hip_runtime.h>
#include <hip/hip_bf16.h>

#define NS 512
#define NB 256
#define NA 16
#define NR_ 256

typedef short s16x8 __attribute__((ext_vector_type(8)));
typedef float f32x4 __attribute__((ext_vector_type(4)));

union BU { uint4 u4; unsigned short us[8]; s16x8 v; unsigned long long ull[2]; };

__device__ __forceinline__ float bf2f(unsigned short h){
  unsigned u = ((unsigned)h) << 16;
  return __builtin_bit_cast(float, u);
}
__device__ __forceinline__ unsigned short f2bf(float f){
  unsigned u = __builtin_bit_cast(unsigned, f);
  u += 0x7fffu + ((u >> 16) & 1u);
  return (unsigned short)(u >> 16);
}
__device__ __forceinline__ float fsig(float x){ return 1.f/(1.f+__expf(-x)); }
__device__ __forceinline__ float ftanh_(float x){ float e=__expf(2.f*x); return 1.f - 2.f/(e+1.f); }

// ---- detect done_flags dtype: u8-bool vs int32 (hdr[0]=1 -> byte format) ----
__global__ void k_detect(const unsigned* __restrict__ done, unsigned* __restrict__ hdr){
  unsigned any = 0;
  for (int i = threadIdx.x; i < 32768; i += 256) any |= (done[i] > 1u) ? 1u : 0u;
  if (__ballot(any)) { if ((threadIdx.x & 63) == 0) atomicOr(hdr, 1u); }
}

__global__ void k_norm(const unsigned char* __restrict__ d8, const int* __restrict__ d32,
                       const unsigned* __restrict__ hdr, unsigned char* __restrict__ dm){
  int i = blockIdx.x*256 + threadIdx.x;
  bool u8 = (hdr[0] & 1u) != 0;
  unsigned char v;
  if (u8) v = (d8[i] != 0) ? 1 : 0; else v = (d32[i] != 0) ? 1 : 0;
  dm[i] = v;
}

// ---- w_ih -> bf16 padded (1024 x 96), bsum = b_ih + b_hh ----
__global__ void k_wbprep(const float* __restrict__ w_ih, const float* __restrict__ b_ih,
                         const float* __restrict__ b_hh, unsigned short* __restrict__ wb,
                         float* __restrict__ bsum){
  const int g = blockIdx.x*256 + threadIdx.x;
  bsum[g] = b_ih[g] + b_hh[g];
  const float* src = w_ih + (size_t)g*81;
  unsigned short* dst = wb + (size_t)g*96;
  for (int k=0;k<81;k++) dst[k]=f2bf(src[k]);
  for (int k=81;k<96;k++) dst[k]=0;
}

// ---- pack w_hh into per-lane MFMA fragment order (layout proven in R4/R5) ----
__global__ void k_wprep2(const float* __restrict__ w_hh, unsigned short* __restrict__ wpack){
  const int G = blockIdx.x*256 + threadIdx.x;   // 0..32767
  const int dw  = G >> 12;
  const int rem = G & 4095;
  const int idx = rem >> 6;
  const int c   = rem & 63;
  const int lp = c >> 4, lr = c & 15;
  const int kt = idx >> 3, mt = idx & 7;
  const int grow = ((mt>>1)<<8) + (dw<<5) + ((mt&1)<<4) + lr;
  const int kcol = (kt<<5) + (lp<<3);
  const float* src = w_hh + (size_t)grow*256 + kcol;
  float4 a = *(const float4*)src;
  float4 b = *(const float4*)(src+4);
  BU u;
  u.us[0]=f2bf(a.x); u.us[1]=f2bf(a.y); u.us[2]=f2bf(a.z); u.us[3]=f2bf(a.w);
  u.us[4]=f2bf(b.x); u.us[5]=f2bf(b.y); u.us[6]=f2bf(b.z); u.us[7]=f2bf(b.w);
  *(uint4*)(wpack + (size_t)G*8) = u.u4;
}

// ---- activations: act[r, 0:96] = [fc(x) | reward | onehot | pad] bf16 ----
__global__ void k_act(const float* __restrict__ input, const float* __restrict__ reward,
                      const int* __restrict__ lastact, const float* __restrict__ fc_w,
                      const float* __restrict__ fc_b, unsigned short* __restrict__ act, int n0){
  __shared__ float wf[1024];
  __shared__ float bfc[64];
  const int tid = threadIdx.x;
  for (int i=tid;i<1024;i+=256) wf[i]=fc_w[i];
  if (tid<64) bfc[tid]=fc_b[tid];
  __syncthreads();
  const int r = blockIdx.x*256 + tid;
  const int n = n0 + r;
  float in[16];
  const float4* ip = (const float4*)(input + (size_t)n*16);
  #pragma unroll
  for (int i=0;i<4;i++){ float4 v=ip[i]; in[4*i]=v.x; in[4*i+1]=v.y; in[4*i+2]=v.z; in[4*i+3]=v.w; }
  unsigned short o[96];
  const float4* wf4=(const float4*)wf;
  #pragma unroll
  for (int q=0;q<64;q++){
    float a=bfc[q];
    #pragma unroll
    for (int k4=0;k4<4;k4++){
      float4 wv=wf4[q*4+k4];
      a += in[4*k4]*wv.x + in[4*k4+1]*wv.y + in[4*k4+2]*wv.z + in[4*k4+3]*wv.w;
    }
    o[q]=f2bf(a);
  }
  o[64]=f2bf(reward[n]);
  const int la = lastact[n];
  #pragma unroll
  for (int k=0;k<16;k++) o[65+k] = (k==la) ? (unsigned short)0x3F80 : (unsigned short)0;
  #pragma unroll
  for (int k=81;k<96;k++) o[k]=0;
  uint4* dst=(uint4*)(act + (size_t)r*96);
  #pragma unroll
  for (int i=0;i<12;i++){
    BU b;
    #pragma unroll
    for (int jj=0;jj<8;jj++) b.us[jj]=o[i*8+jj];
    dst[i]=b.u4;
  }
}

// ---- Xg GEMM: xg[M,1024] = act[M,96] @ wb[1024,96]^T + bsum, bf16 out ----
__launch_bounds__(256,1) __global__ void k_gemm(
    const unsigned short* __restrict__ act, const unsigned short* __restrict__ wb,
    const float* __restrict__ bsum, unsigned short* __restrict__ xg, int mtiles){
  __shared__ __align__(16) unsigned short lA[128*104];
  __shared__ __align__(16) unsigned short lB[128*104];
  const int bm = blockIdx.x % mtiles;
  const int bn = blockIdx.x / mtiles;
  const int tid = threadIdx.x;
  {
    const int r = tid >> 1, sg = tid & 1;
    const uint4* sa = (const uint4*)(act + (size_t)(bm*128 + r)*96 + sg*48);
    const uint4* sb = (const uint4*)(wb  + (size_t)(bn*128 + r)*96 + sg*48);
    uint4* da = (uint4*)&lA[r*104 + sg*48];
    uint4* db = (uint4*)&lB[r*104 + sg*48];
    #pragma unroll
    for (int i=0;i<6;i++){ da[i]=sa[i]; db[i]=sb[i]; }
  }
  __syncthreads();
  const int wid = tid >> 6, lane = tid & 63;
  const int wm = wid >> 1, wn = wid & 1;
  const int lr = lane & 15, lp = lane >> 4;
  f32x4 acc[4][4] = {};
  #pragma unroll
  for (int kt=0;kt<3;kt++){
    s16x8 af[4], bf[4];
    #pragma unroll
    for (int mi=0;mi<4;mi++)
      af[mi] = *(const s16x8*)&lA[(wm*64 + mi*16 + lr)*104 + kt*32 + lp*8];
    #pragma unroll
    for (int ni=0;ni<4;ni++)
      bf[ni] = *(const s16x8*)&lB[(wn*64 + ni*16 + lr)*104 + kt*32 + lp*8];
    #pragma unroll
    for (int mi=0;mi<4;mi++){
      #pragma unroll
      for (int ni=0;ni<4;ni++)
        acc[mi][ni] = __builtin_amdgcn_mfma_f32_16x16x32_bf16(af[mi], bf[ni], acc[mi][ni], 0,0,0);
    }
  }
  #pragma unroll
  for (int ni=0;ni<4;ni++){
    const int col = bn*128 + wn*64 + ni*16 + lr;
    const float bias = bsum[col];
    #pragma unroll
    for (int mi=0;mi<4;mi++){
      const int row = bm*128 + wm*64 + mi*16 + lp*4;
      #pragma unroll
      for (int rr=0;rr<4;rr++)
        xg[((size_t)(row+rr)<<10) + col] = f2bf(acc[mi][ni][rr] + bias);
    }
  }
}

// ---- persistent LSTM core (R7 = R6 + hs-store fix): 16 WGs, 8 waves, no arrays ----
// Weights: kt 0..1 (16 frags/wave) in LDS 128KB; kt 2..7 = 48 NAMED s16x8
// register fragments. Fix vs R6: half=1 hs store offset is +4 ull (+16 shorts),
// was +2 ull (+8 shorts) -> corrupted h history.
#define MFMA_ __builtin_amdgcn_mfma_f32_16x16x32_bf16
#define LDSF(KT,MT) (*(const s16x8*)&LW2[(w<<13)+(((KT)*8+(MT))<<9)+(lane<<3)])
#define WLOAD(KT,MT) const s16x8 wf##KT##_##MT = \
  *(const s16x8*)(wpack + ((size_t)w<<15) + (((KT)*8+(MT))<<9) + (lane<<3));
#define WLOADKT(KT) WLOAD(KT,0) WLOAD(KT,1) WLOAD(KT,2) WLOAD(KT,3) \
                    WLOAD(KT,4) WLOAD(KT,5) WLOAD(KT,6) WLOAD(KT,7)
#define QUAD(KT, B0,B1,B2,B3, A0,A1,A2,A3) { \
  BU bu_; bu_.u4 = *(const uint4*)&HB[((KT)<<9)+(lane<<3)]; \
  if (dnc) bu_.u4 = make_uint4(0,0,0,0); \
  B0 = MFMA_(A0, bu_.v, B0, 0,0,0); \
  B1 = MFMA_(A1, bu_.v, B1, 0,0,0); \
  B2 = MFMA_(A2, bu_.v, B2, 0,0,0); \
  B3 = MFMA_(A3, bu_.v, B3, 0,0,0); }
#define EPI(RR, QF, QO, XF, XO, CREG, UREG, HREG) { \
  float cp_ = dnc ? 0.f : CREG; \
  float ff_ = fsig(QF[RR]+bf2f(XF)); \
  float oo_ = fsig(QO[RR]+bf2f(XO)); \
  float cn_ = ff_*cp_ + UREG; \
  CREG = cn_; HREG = f2bf(oo_*ftanh_(cn_)); }

__launch_bounds__(512,2) __global__ void k_main(
    const float* __restrict__ hidden, const unsigned short* __restrict__ xg,
    const unsigned char* __restrict__ dm, const unsigned short* __restrict__ wpack,
    unsigned short* __restrict__ hs, float* __restrict__ cstate, int t0, int CH){
  __shared__ __align__(16) unsigned short LW2[65536]; // 128KB: [wave][frag kt<2]
  __shared__ __align__(16) unsigned short HB[4096];   // 8KB h buffer
  const int tid = threadIdx.x;
  const int wg = blockIdx.x;
  const int w  = tid >> 6;
  const int lane = tid & 63;
  const int lr = lane & 15, lp = lane >> 4;
  const int bglob = (wg << 4) + lr;

  // stage LDS weights (pre-packed, linear): frags idx 0..15 per wave
  for (int it = tid; it < 8192; it += 512){
    int dw = it >> 10, rem = it & 1023;
    *(uint4*)&LW2[(dw<<13) + rem*8] = *(const uint4*)(wpack + ((size_t)dw<<15) + rem*8);
  }
  // 48 named register fragments (kt 2..7)
  WLOADKT(2) WLOADKT(3) WLOADKT(4) WLOADKT(5) WLOADKT(6) WLOADKT(7)

  // h init into HB
  {
    const int k0 = (w<<5) + (lp<<3);
    BU u;
    if (t0 == 0){
      const float* src = hidden + (size_t)bglob*256 + k0;
      float4 a = *(const float4*)src, b = *(const float4*)(src+4);
      u.us[0]=f2bf(a.x); u.us[1]=f2bf(a.y); u.us[2]=f2bf(a.z); u.us[3]=f2bf(a.w);
      u.us[4]=f2bf(b.x); u.us[5]=f2bf(b.y); u.us[6]=f2bf(b.z); u.us[7]=f2bf(b.w);
    } else {
      u.u4 = *(const uint4*)(hs + ((size_t)((CH-1)*NB + bglob) << 8) + k0);
    }
    *(uint4*)&HB[(w<<9) + ((lp<<4)+lr)*8] = u.u4;
  }
  // c init: named scalars; lane's rows r = w*32 + half*16 + lp*4 + rr
  float c0,c1,c2,c3,c4,c5,c6,c7;
  {
    const float* csrc = (t0 == 0) ? (hidden + 65536) : cstate;
    float4 cv0 = *(const float4*)(csrc + (size_t)bglob*256 + (w<<5) + (lp<<2));
    float4 cv1 = *(const float4*)(csrc + (size_t)bglob*256 + (w<<5) + 16 + (lp<<2));
    c0=cv0.x; c1=cv0.y; c2=cv0.z; c3=cv0.w;
    c4=cv1.x; c5=cv1.y; c6=cv1.z; c7=cv1.w;
  }
  __syncthreads();

  for (int s = 0; s < CH; ++s){
    const bool dnc = dm[(t0+s)*NB + bglob] != 0;
    const unsigned short* xrow = xg + ((size_t)(s*NB + bglob) << 10) + (w<<5) + (lp<<2);
    // phase-1 xg: gate i (0) and gate g (2)
    ushort4 xi0 = *(const ushort4*)(xrow);
    ushort4 xi1 = *(const ushort4*)(xrow + 16);
    ushort4 xG0 = *(const ushort4*)(xrow + 512);
    ushort4 xG1 = *(const ushort4*)(xrow + 528);

    // PHASE 1: i (mt 0,1), g (mt 4,5)
    f32x4 p0={0.f,0.f,0.f,0.f}, p1=p0, p2=p0, p3=p0;
    QUAD(0, p0,p1,p2,p3, LDSF(0,0), LDSF(0,1), LDSF(0,4), LDSF(0,5))
    QUAD(1, p0,p1,p2,p3, LDSF(1,0), LDSF(1,1), LDSF(1,4), LDSF(1,5))
    QUAD(2, p0,p1,p2,p3, wf2_0, wf2_1, wf2_4, wf2_5)
    QUAD(3, p0,p1,p2,p3, wf3_0, wf3_1, wf3_4, wf3_5)
    QUAD(4, p0,p1,p2,p3, wf4_0, wf4_1, wf4_4, wf4_5)
    QUAD(5, p0,p1,p2,p3, wf5_0, wf5_1, wf5_4, wf5_5)
    QUAD(6, p0,p1,p2,p3, wf6_0, wf6_1, wf6_4, wf6_5)
    QUAD(7, p0,p1,p2,p3, wf7_0, wf7_1, wf7_4, wf7_5)

    float u0 = fsig(p0[0]+bf2f(xi0.x)) * ftanh_(p2[0]+bf2f(xG0.x));
    float u1 = fsig(p0[1]+bf2f(xi0.y)) * ftanh_(p2[1]+bf2f(xG0.y));
    float u2 = fsig(p0[2]+bf2f(xi0.z)) * ftanh_(p2[2]+bf2f(xG0.z));
    float u3 = fsig(p0[3]+bf2f(xi0.w)) * ftanh_(p2[3]+bf2f(xG0.w));
    float u4 = fsig(p1[0]+bf2f(xi1.x)) * ftanh_(p3[0]+bf2f(xG1.x));
    float u5 = fsig(p1[1]+bf2f(xi1.y)) * ftanh_(p3[1]+bf2f(xG1.y));
    float u6 = fsig(p1[2]+bf2f(xi1.z)) * ftanh_(p3[2]+bf2f(xG1.z));
    float u7 = fsig(p1[3]+bf2f(xi1.w)) * ftanh_(p3[3]+bf2f(xG1.w));

    // PHASE 2: f (mt 2,3), o (mt 6,7)
    ushort4 xf0 = *(const ushort4*)(xrow + 256);
    ushort4 xf1 = *(const ushort4*)(xrow + 272);
    ushort4 xo0 = *(const ushort4*)(xrow + 768);
    ushort4 xo1 = *(const ushort4*)(xrow + 784);
    f32x4 q0={0.f,0.f,0.f,0.f}, q1=q0, q2=q0, q3=q0;
    QUAD(0, q0,q1,q2,q3, LDSF(0,2), LDSF(0,3), LDSF(0,6), LDSF(0,7))
    QUAD(1, q0,q1,q2,q3, LDSF(1,2), LDSF(1,3), LDSF(1,6), LDSF(1,7))
    QUAD(2, q0,q1,q2,q3, wf2_2, wf2_3, wf2_6, wf2_7)
    QUAD(3, q0,q1,q2,q3, wf3_2, wf3_3, wf3_6, wf3_7)
    QUAD(4, q0,q1,q2,q3, wf4_2, wf4_3, wf4_6, wf4_7)
    QUAD(5, q0,q1,q2,q3, wf5_2, wf5_3, wf5_6, wf5_7)
    QUAD(6, q0,q1,q2,q3, wf6_2, wf6_3, wf6_6, wf6_7)
    QUAD(7, q0,q1,q2,q3, wf7_2, wf7_3, wf7_6, wf7_7)

    unsigned short h0,h1,h2,h3,h4,h5,h6,h7;
    EPI(0, q0,q2, xf0.x, xo0.x, c0, u0, h0)
    EPI(1, q0,q2, xf0.y, xo0.y, c1, u1, h1)
    EPI(2, q0,q2, xf0.z, xo0.z, c2, u2, h2)
    EPI(3, q0,q2, xf0.w, xo0.w, c3, u3, h3)
    EPI(0, q1,q3, xf1.x, xo1.x, c4, u4, h4)
    EPI(1, q1,q3, xf1.y, xo1.y, c5, u5, h5)
    EPI(2, q1,q3, xf1.z, xo1.z, c6, u6, h6)
    EPI(3, q1,q3, xf1.w, xo1.w, c7, u7, h7)

    __syncthreads();   // all waves done reading h(t-1) from HB
    unsigned long long hpA = (unsigned long long)h0 | ((unsigned long long)h1<<16)
                           | ((unsigned long long)h2<<32) | ((unsigned long long)h3<<48);
    unsigned long long hpB = (unsigned long long)h4 | ((unsigned long long)h5<<16)
                           | ((unsigned long long)h6<<32) | ((unsigned long long)h7<<48);
    *(unsigned long long*)&HB[(w<<9) + (((lp>>1)<<4) + lr)*8 + ((lp&1)<<2)] = hpA;
    *(unsigned long long*)&HB[(w<<9) + (((2+(lp>>1))<<4) + lr)*8 + ((lp&1)<<2)] = hpB;
    unsigned long long* hdst =
      (unsigned long long*)(hs + ((size_t)(s*NB + bglob) << 8) + (w<<5) + (lp<<2));
    hdst[0] = hpA;
    hdst[4] = hpB;   // +16 shorts = +4 ull  (R6 bug: was [2])
    __syncthreads();   // h(t) ready in HB
  }
  *(float4*)(cstate + (size_t)bglob*256 + (w<<5) + (lp<<2)) = make_float4(c0,c1,c2,c3);
  *(float4*)(cstate + (size_t)bglob*256 + (w<<5) + 16 + (lp<<2)) = make_float4(c4,c5,c6,c7);
}

// ---- heads: logits = hs@actor_w.T + b ; values = hs@critic_w.T + b ----
__launch_bounds__(64,1) __global__ void k_proj(
    const unsigned short* __restrict__ hs, const float* __restrict__ actor_w,
    const float* __restrict__ actor_b, const float* __restrict__ critic_w,
    const float* __restrict__ critic_b, float* __restrict__ outL, float* __restrict__ outV){
  const int lane = threadIdx.x;
  const int m0 = blockIdx.x * 64;
  const int lr = lane & 15, lp = lane >> 4;
  f32x4 acc[4] = {};
  float part[4] = {0.f,0.f,0.f,0.f};
  #pragma unroll
  for (int kt=0;kt<8;kt++){
    BU bw;
    const float4* ap = (const float4*)(actor_w + (size_t)lr*256 + (kt<<5) + (lp<<3));
    float4 w0=ap[0], w1=ap[1];
    bw.us[0]=f2bf(w0.x); bw.us[1]=f2bf(w0.y); bw.us[2]=f2bf(w0.z); bw.us[3]=f2bf(w0.w);
    bw.us[4]=f2bf(w1.x); bw.us[5]=f2bf(w1.y); bw.us[6]=f2bf(w1.z); bw.us[7]=f2bf(w1.w);
    const float4* cp4 = (const float4*)(critic_w + (kt<<5) + (lp<<3));
    float4 cw0=cp4[0], cw1=cp4[1];
    #pragma unroll
    for (int mi=0;mi<4;mi++){
      BU hv; hv.u4 = *(const uint4*)(hs + ((size_t)(m0 + mi*16 + lr) << 8) + (kt<<5) + (lp<<3));
      acc[mi] = __builtin_amdgcn_mfma_f32_16x16x32_bf16(hv.v, bw.v, acc[mi], 0,0,0);
      part[mi] += bf2f(hv.us[0])*cw0.x + bf2f(hv.us[1])*cw0.y + bf2f(hv.us[2])*cw0.z + bf2f(hv.us[3])*cw0.w
                + bf2f(hv.us[4])*cw1.x + bf2f(hv.us[5])*cw1.y + bf2f(hv.us[6])*cw1.z + bf2f(hv.us[7])*cw1.w;
    }
  }
  const float ab = actor_b[lr];
  #pragma unroll
  for (int mi=0;mi<4;mi++){
    #pragma unroll
    for (int rr=0;rr<4;rr++)
      outL[(size_t)(m0 + mi*16 + lp*4 + rr)*16 + lr] = acc[mi][rr] + ab;
  }
  const float cb = critic_b[0];
  #pragma unroll
  for (int mi=0;mi<4;mi++){
    float v = part[mi];
    v += __shfl_xor(v, 16, 64);
    v += __shfl_xor(v, 32, 64);
    if (lp == 0) outV[m0 + mi*16 + lr] = v + cb;
  }
}

extern "C" void kernel_launch(void* const* d_in, const int* in_sizes, int n_in,
                              void* d_out, int out_size, void* d_ws, size_t ws_size,
                              hipStream_t stream) {
  (void)in_sizes; (void)n_in; (void)out_size;
  const float* input    = (const float*)d_in[0];
  const int*   lastact  = (const int*)d_in[1];
  const float* reward   = (const float*)d_in[2];
  const void*  done     = d_in[3];
  const float* hidden   = (const float*)d_in[4];
  const float* fc_w     = (const float*)d_in[5];
  const float* fc_b     = (const float*)d_in[6];
  const float* w_ih     = (const float*)d_in[7];
  const float* w_hh     = (const float*)d_in[8];
  const float* b_ih     = (const float*)d_in[9];
  const float* b_hh     = (const float*)d_in[10];
  const float* actor_w  = (const float*)d_in[11];
  const float* actor_b  = (const float*)d_in[12];
  const float* critic_w = (const float*)d_in[13];
  const float* critic_b = (const float*)d_in[14];
  float* outL = (float*)d_out;
  float* outV = outL + (size_t)NS*NA*NB;

  char* p = (char*)d_ws;
  unsigned*       hdr    = (unsigned*)p;                           // 256B
  unsigned char*  dmb    = (unsigned char*)(p + 1024);             // 131072
  unsigned short* wb     = (unsigned short*)(p + 132096);          // 196608
  float*          bsum   = (float*)(p + 328704);                   // 4096
  float*          cstate = (float*)(p + 332800);                   // 262144
  unsigned short* wpack  = (unsigned short*)(p + 594944);          // 524288
  const size_t fixed = 1119232;
  int CH = 128;   // xg (64MB) + hs (16MB) stay L3-resident per chunk
  while (CH > 4){
    size_t need = fixed + (size_t)CH*49152 + (size_t)CH*524288 + (size_t)CH*131072;
    if (need <= ws_size) break;
    CH >>= 1;
  }
  unsigned short* act = (unsigned short*)(p + fixed);
  unsigned short* xg  = (unsigned short*)(p + fixed + (size_t)CH*49152);
  unsigned short* hs  = (unsigned short*)(p + fixed + (size_t)CH*49152 + (size_t)CH*524288);

  hipMemsetAsync(d_ws, 0, 1024, stream);
  hipLaunchKernelGGL(k_detect, dim3(1), dim3(256), 0, stream, (const unsigned*)done, hdr);
  hipLaunchKernelGGL(k_norm, dim3(512), dim3(256), 0, stream,
                     (const unsigned char*)done, (const int*)done, hdr, dmb);
  hipLaunchKernelGGL(k_wbprep, dim3(4), dim3(256), 0, stream, w_ih, b_ih, b_hh, wb, bsum);
  hipLaunchKernelGGL(k_wprep2, dim3(128), dim3(256), 0, stream, w_hh, wpack);

  const int NC = NS / CH;
  for (int c = 0; c < NC; ++c){
    const int t0 = c * CH;
    hipLaunchKernelGGL(k_act, dim3(CH), dim3(256), 0, stream,
                       input, reward, lastact, fc_w, fc_b, act, t0*NB);
    hipLaunchKernelGGL(k_gemm, dim3(CH*2*8), dim3(256), 0, stream, act, wb, bsum, xg, CH*2);
    hipLaunchKernelGGL(k_main, dim3(16), dim3(512), 0, stream,
                       hidden, xg, dmb, wpack, hs, cstate, t0, CH);
    hipLaunchKernelGGL(k_proj, dim3(CH*4), dim3(64), 0, stream,
                       hs, actor_w, actor_b, critic_w, critic_b,
                       outL + (size_t)t0*NB*NA, outV + (size_t)t0*NB);
  }
}

// Round 8
// 3367.160 us; speedup vs baseline: 1.0853x; 1.0853x over previous
//
#include <hip/hip_runtime.h>
#include <hip/hip_bf16.h>

#define NS 512
#define NB 256
#define NA 16
#define NR_ 256

typedef short s16x8 __attribute__((ext_vector_type(8)));
typedef float f32x4 __attribute__((ext_vector_type(4)));

union BU { uint4 u4; unsigned short us[8]; s16x8 v; unsigned long long ull[2]; };

__device__ __forceinline__ float bf2f(unsigned short h){
  unsigned u = ((unsigned)h) << 16;
  return __builtin_bit_cast(float, u);
}
__device__ __forceinline__ unsigned short f2bf(float f){
  unsigned u = __builtin_bit_cast(unsigned, f);
  u += 0x7fffu + ((u >> 16) & 1u);
  return (unsigned short)(u >> 16);
}
__device__ __forceinline__ float fsig(float x){ return 1.f/(1.f+__expf(-x)); }
__device__ __forceinline__ float ftanh_(float x){ float e=__expf(2.f*x); return 1.f - 2.f/(e+1.f); }

// ---- detect done_flags dtype: u8-bool vs int32 (hdr[0]=1 -> byte format) ----
__global__ void k_detect(const unsigned* __restrict__ done, unsigned* __restrict__ hdr){
  unsigned any = 0;
  for (int i = threadIdx.x; i < 32768; i += 256) any |= (done[i] > 1u) ? 1u : 0u;
  if (__ballot(any)) { if ((threadIdx.x & 63) == 0) atomicOr(hdr, 1u); }
}

__global__ void k_norm(const unsigned char* __restrict__ d8, const int* __restrict__ d32,
                       const unsigned* __restrict__ hdr, unsigned char* __restrict__ dm){
  int i = blockIdx.x*256 + threadIdx.x;
  bool u8 = (hdr[0] & 1u) != 0;
  unsigned char v;
  if (u8) v = (d8[i] != 0) ? 1 : 0; else v = (d32[i] != 0) ? 1 : 0;
  dm[i] = v;
}

// ---- w_ih -> bf16 padded (1024 x 96), bsum = b_ih + b_hh ----
__global__ void k_wbprep(const float* __restrict__ w_ih, const float* __restrict__ b_ih,
                         const float* __restrict__ b_hh, unsigned short* __restrict__ wb,
                         float* __restrict__ bsum){
  const int g = blockIdx.x*256 + threadIdx.x;
  bsum[g] = b_ih[g] + b_hh[g];
  const float* src = w_ih + (size_t)g*81;
  unsigned short* dst = wb + (size_t)g*96;
  for (int k=0;k<81;k++) dst[k]=f2bf(src[k]);
  for (int k=81;k<96;k++) dst[k]=0;
}

// ---- pack w_hh into per-lane MFMA fragment order (layout proven in R4/R5/R7) ----
__global__ void k_wprep2(const float* __restrict__ w_hh, unsigned short* __restrict__ wpack){
  const int G = blockIdx.x*256 + threadIdx.x;   // 0..32767
  const int dw  = G >> 12;
  const int rem = G & 4095;
  const int idx = rem >> 6;
  const int c   = rem & 63;
  const int lp = c >> 4, lr = c & 15;
  const int kt = idx >> 3, mt = idx & 7;
  const int grow = ((mt>>1)<<8) + (dw<<5) + ((mt&1)<<4) + lr;
  const int kcol = (kt<<5) + (lp<<3);
  const float* src = w_hh + (size_t)grow*256 + kcol;
  float4 a = *(const float4*)src;
  float4 b = *(const float4*)(src+4);
  BU u;
  u.us[0]=f2bf(a.x); u.us[1]=f2bf(a.y); u.us[2]=f2bf(a.z); u.us[3]=f2bf(a.w);
  u.us[4]=f2bf(b.x); u.us[5]=f2bf(b.y); u.us[6]=f2bf(b.z); u.us[7]=f2bf(b.w);
  *(uint4*)(wpack + (size_t)G*8) = u.u4;
}

// ---- activations: act[r, 0:96] = [fc(x) | reward | onehot | pad] bf16 ----
__global__ void k_act(const float* __restrict__ input, const float* __restrict__ reward,
                      const int* __restrict__ lastact, const float* __restrict__ fc_w,
                      const float* __restrict__ fc_b, unsigned short* __restrict__ act, int n0){
  __shared__ float wf[1024];
  __shared__ float bfc[64];
  const int tid = threadIdx.x;
  for (int i=tid;i<1024;i+=256) wf[i]=fc_w[i];
  if (tid<64) bfc[tid]=fc_b[tid];
  __syncthreads();
  const int r = blockIdx.x*256 + tid;
  const int n = n0 + r;
  float in[16];
  const float4* ip = (const float4*)(input + (size_t)n*16);
  #pragma unroll
  for (int i=0;i<4;i++){ float4 v=ip[i]; in[4*i]=v.x; in[4*i+1]=v.y; in[4*i+2]=v.z; in[4*i+3]=v.w; }
  unsigned short o[96];
  const float4* wf4=(const float4*)wf;
  #pragma unroll
  for (int q=0;q<64;q++){
    float a=bfc[q];
    #pragma unroll
    for (int k4=0;k4<4;k4++){
      float4 wv=wf4[q*4+k4];
      a += in[4*k4]*wv.x + in[4*k4+1]*wv.y + in[4*k4+2]*wv.z + in[4*k4+3]*wv.w;
    }
    o[q]=f2bf(a);
  }
  o[64]=f2bf(reward[n]);
  const int la = lastact[n];
  #pragma unroll
  for (int k=0;k<16;k++) o[65+k] = (k==la) ? (unsigned short)0x3F80 : (unsigned short)0;
  #pragma unroll
  for (int k=81;k<96;k++) o[k]=0;
  uint4* dst=(uint4*)(act + (size_t)r*96);
  #pragma unroll
  for (int i=0;i<12;i++){
    BU b;
    #pragma unroll
    for (int jj=0;jj<8;jj++) b.us[jj]=o[i*8+jj];
    dst[i]=b.u4;
  }
}

// ---- Xg GEMM: xg[M,1024] = act[M,96] @ wb[1024,96]^T + bsum, bf16 out ----
__launch_bounds__(256,1) __global__ void k_gemm(
    const unsigned short* __restrict__ act, const unsigned short* __restrict__ wb,
    const float* __restrict__ bsum, unsigned short* __restrict__ xg, int mtiles){
  __shared__ __align__(16) unsigned short lA[128*104];
  __shared__ __align__(16) unsigned short lB[128*104];
  const int bm = blockIdx.x % mtiles;
  const int bn = blockIdx.x / mtiles;
  const int tid = threadIdx.x;
  {
    const int r = tid >> 1, sg = tid & 1;
    const uint4* sa = (const uint4*)(act + (size_t)(bm*128 + r)*96 + sg*48);
    const uint4* sb = (const uint4*)(wb  + (size_t)(bn*128 + r)*96 + sg*48);
    uint4* da = (uint4*)&lA[r*104 + sg*48];
    uint4* db = (uint4*)&lB[r*104 + sg*48];
    #pragma unroll
    for (int i=0;i<6;i++){ da[i]=sa[i]; db[i]=sb[i]; }
  }
  __syncthreads();
  const int wid = tid >> 6, lane = tid & 63;
  const int wm = wid >> 1, wn = wid & 1;
  const int lr = lane & 15, lp = lane >> 4;
  f32x4 acc[4][4] = {};
  #pragma unroll
  for (int kt=0;kt<3;kt++){
    s16x8 af[4], bf[4];
    #pragma unroll
    for (int mi=0;mi<4;mi++)
      af[mi] = *(const s16x8*)&lA[(wm*64 + mi*16 + lr)*104 + kt*32 + lp*8];
    #pragma unroll
    for (int ni=0;ni<4;ni++)
      bf[ni] = *(const s16x8*)&lB[(wn*64 + ni*16 + lr)*104 + kt*32 + lp*8];
    #pragma unroll
    for (int mi=0;mi<4;mi++){
      #pragma unroll
      for (int ni=0;ni<4;ni++)
        acc[mi][ni] = __builtin_amdgcn_mfma_f32_16x16x32_bf16(af[mi], bf[ni], acc[mi][ni], 0,0,0);
    }
  }
  #pragma unroll
  for (int ni=0;ni<4;ni++){
    const int col = bn*128 + wn*64 + ni*16 + lr;
    const float bias = bsum[col];
    #pragma unroll
    for (int mi=0;mi<4;mi++){
      const int row = bm*128 + wm*64 + mi*16 + lp*4;
      #pragma unroll
      for (int rr=0;rr<4;rr++)
        xg[((size_t)(row+rr)<<10) + col] = f2bf(acc[mi][ni][rr] + bias);
    }
  }
}

// ---- persistent LSTM core (R8): 16 WGs, 8 waves, PINNED register weights ----
// 18 frags/wave in LDS (144KB); 46 frags/wave (184 VGPR) pinned via opaque
// asm defs (cannot be re-materialized); amdgpu_waves_per_eu(2,2) gives the
// allocator the full 256-reg/wave budget with no occupancy incentive to shrink.
#define MFMA_ __builtin_amdgcn_mfma_f32_16x16x32_bf16
#define LDSF(KT,MT) (*(const s16x8*)&LW2[w*9216 + (((KT)*8+(MT))<<9) + (lane<<3)])
#define WLOADP(KT,MT) s16x8 wf##KT##_##MT = \
  *(const s16x8*)(wpack + ((size_t)w<<15) + (((KT)*8+(MT))<<9) + (lane<<3)); \
  asm volatile("" : "+v"(wf##KT##_##MT));
#define WLOADKT(KT) WLOADP(KT,0) WLOADP(KT,1) WLOADP(KT,2) WLOADP(KT,3) \
                    WLOADP(KT,4) WLOADP(KT,5) WLOADP(KT,6) WLOADP(KT,7)
#define QUAD(KT, B0,B1,B2,B3, A0,A1,A2,A3) { \
  BU bu_; bu_.u4 = *(const uint4*)&HB[((KT)<<9)+(lane<<3)]; \
  if (dnc) bu_.u4 = make_uint4(0,0,0,0); \
  B0 = MFMA_(A0, bu_.v, B0, 0,0,0); \
  B1 = MFMA_(A1, bu_.v, B1, 0,0,0); \
  B2 = MFMA_(A2, bu_.v, B2, 0,0,0); \
  B3 = MFMA_(A3, bu_.v, B3, 0,0,0); }
#define EPI(RR, QF, QO, XF, XO, CREG, UREG, HREG) { \
  float cp_ = dnc ? 0.f : CREG; \
  float ff_ = fsig(QF[RR]+bf2f(XF)); \
  float oo_ = fsig(QO[RR]+bf2f(XO)); \
  float cn_ = ff_*cp_ + UREG; \
  CREG = cn_; HREG = f2bf(oo_*ftanh_(cn_)); }

__global__ __launch_bounds__(512) __attribute__((amdgpu_waves_per_eu(2,2)))
void k_main(
    const float* __restrict__ hidden, const unsigned short* __restrict__ xg,
    const unsigned char* __restrict__ dm, const unsigned short* __restrict__ wpack,
    unsigned short* __restrict__ hs, float* __restrict__ cstate, int t0, int CH){
  __shared__ __align__(16) unsigned short LW2[73728]; // 144KB: [wave][frag idx<18]
  __shared__ __align__(16) unsigned short HB[4096];   // 8KB h buffer
  const int tid = threadIdx.x;
  const int wg = blockIdx.x;
  const int w  = tid >> 6;
  const int lane = tid & 63;
  const int lr = lane & 15, lp = lane >> 4;
  const int bglob = (wg << 4) + lr;

  // stage LDS weights (pre-packed, linear): frag idx 0..17 per wave
  for (int it = tid; it < 9216; it += 512){
    int dw = it / 1152;                 // 1152 = 18 frags * 64 chunks
    int rem = it - dw*1152;
    *(uint4*)&LW2[dw*9216 + rem*8] =
      *(const uint4*)(wpack + (size_t)dw*32768 + (size_t)rem*8);
  }
  // 46 pinned register fragments: kt2 mt2..7, kt3..7 all (idx 18..63)
  WLOADP(2,2) WLOADP(2,3) WLOADP(2,4) WLOADP(2,5) WLOADP(2,6) WLOADP(2,7)
  WLOADKT(3) WLOADKT(4) WLOADKT(5) WLOADKT(6) WLOADKT(7)

  // h init into HB
  {
    const int k0 = (w<<5) + (lp<<3);
    BU u;
    if (t0 == 0){
      const float* src = hidden + (size_t)bglob*256 + k0;
      float4 a = *(const float4*)src, b = *(const float4*)(src+4);
      u.us[0]=f2bf(a.x); u.us[1]=f2bf(a.y); u.us[2]=f2bf(a.z); u.us[3]=f2bf(a.w);
      u.us[4]=f2bf(b.x); u.us[5]=f2bf(b.y); u.us[6]=f2bf(b.z); u.us[7]=f2bf(b.w);
    } else {
      u.u4 = *(const uint4*)(hs + ((size_t)((CH-1)*NB + bglob) << 8) + k0);
    }
    *(uint4*)&HB[(w<<9) + ((lp<<4)+lr)*8] = u.u4;
  }
  // c init: named scalars; lane's rows r = w*32 + half*16 + lp*4 + rr
  float c0,c1,c2,c3,c4,c5,c6,c7;
  {
    const float* csrc = (t0 == 0) ? (hidden + 65536) : cstate;
    float4 cv0 = *(const float4*)(csrc + (size_t)bglob*256 + (w<<5) + (lp<<2));
    float4 cv1 = *(const float4*)(csrc + (size_t)bglob*256 + (w<<5) + 16 + (lp<<2));
    c0=cv0.x; c1=cv0.y; c2=cv0.z; c3=cv0.w;
    c4=cv1.x; c5=cv1.y; c6=cv1.z; c7=cv1.w;
  }
  __syncthreads();

  for (int s = 0; s < CH; ++s){
    const bool dnc = dm[(t0+s)*NB + bglob] != 0;
    const unsigned short* xrow = xg + ((size_t)(s*NB + bglob) << 10) + (w<<5) + (lp<<2);
    // phase-1 xg: gate i (0) and gate g (2)
    ushort4 xi0 = *(const ushort4*)(xrow);
    ushort4 xi1 = *(const ushort4*)(xrow + 16);
    ushort4 xG0 = *(const ushort4*)(xrow + 512);
    ushort4 xG1 = *(const ushort4*)(xrow + 528);

    // PHASE 1: i (mt 0,1), g (mt 4,5)
    f32x4 p0={0.f,0.f,0.f,0.f}, p1=p0, p2=p0, p3=p0;
    QUAD(0, p0,p1,p2,p3, LDSF(0,0), LDSF(0,1), LDSF(0,4), LDSF(0,5))
    QUAD(1, p0,p1,p2,p3, LDSF(1,0), LDSF(1,1), LDSF(1,4), LDSF(1,5))
    QUAD(2, p0,p1,p2,p3, LDSF(2,0), LDSF(2,1), wf2_4, wf2_5)
    QUAD(3, p0,p1,p2,p3, wf3_0, wf3_1, wf3_4, wf3_5)
    QUAD(4, p0,p1,p2,p3, wf4_0, wf4_1, wf4_4, wf4_5)
    QUAD(5, p0,p1,p2,p3, wf5_0, wf5_1, wf5_4, wf5_5)
    QUAD(6, p0,p1,p2,p3, wf6_0, wf6_1, wf6_4, wf6_5)
    QUAD(7, p0,p1,p2,p3, wf7_0, wf7_1, wf7_4, wf7_5)

    float u0 = fsig(p0[0]+bf2f(xi0.x)) * ftanh_(p2[0]+bf2f(xG0.x));
    float u1 = fsig(p0[1]+bf2f(xi0.y)) * ftanh_(p2[1]+bf2f(xG0.y));
    float u2 = fsig(p0[2]+bf2f(xi0.z)) * ftanh_(p2[2]+bf2f(xG0.z));
    float u3 = fsig(p0[3]+bf2f(xi0.w)) * ftanh_(p2[3]+bf2f(xG0.w));
    float u4 = fsig(p1[0]+bf2f(xi1.x)) * ftanh_(p3[0]+bf2f(xG1.x));
    float u5 = fsig(p1[1]+bf2f(xi1.y)) * ftanh_(p3[1]+bf2f(xG1.y));
    float u6 = fsig(p1[2]+bf2f(xi1.z)) * ftanh_(p3[2]+bf2f(xG1.z));
    float u7 = fsig(p1[3]+bf2f(xi1.w)) * ftanh_(p3[3]+bf2f(xG1.w));

    // PHASE 2: f (mt 2,3), o (mt 6,7)
    ushort4 xf0 = *(const ushort4*)(xrow + 256);
    ushort4 xf1 = *(const ushort4*)(xrow + 272);
    ushort4 xo0 = *(const ushort4*)(xrow + 768);
    ushort4 xo1 = *(const ushort4*)(xrow + 784);
    f32x4 q0={0.f,0.f,0.f,0.f}, q1=q0, q2=q0, q3=q0;
    QUAD(0, q0,q1,q2,q3, LDSF(0,2), LDSF(0,3), LDSF(0,6), LDSF(0,7))
    QUAD(1, q0,q1,q2,q3, LDSF(1,2), LDSF(1,3), LDSF(1,6), LDSF(1,7))
    QUAD(2, q0,q1,q2,q3, wf2_2, wf2_3, wf2_6, wf2_7)
    QUAD(3, q0,q1,q2,q3, wf3_2, wf3_3, wf3_6, wf3_7)
    QUAD(4, q0,q1,q2,q3, wf4_2, wf4_3, wf4_6, wf4_7)
    QUAD(5, q0,q1,q2,q3, wf5_2, wf5_3, wf5_6, wf5_7)
    QUAD(6, q0,q1,q2,q3, wf6_2, wf6_3, wf6_6, wf6_7)
    QUAD(7, q0,q1,q2,q3, wf7_2, wf7_3, wf7_6, wf7_7)

    unsigned short h0,h1,h2,h3,h4,h5,h6,h7;
    EPI(0, q0,q2, xf0.x, xo0.x, c0, u0, h0)
    EPI(1, q0,q2, xf0.y, xo0.y, c1, u1, h1)
    EPI(2, q0,q2, xf0.z, xo0.z, c2, u2, h2)
    EPI(3, q0,q2, xf0.w, xo0.w, c3, u3, h3)
    EPI(0, q1,q3, xf1.x, xo1.x, c4, u4, h4)
    EPI(1, q1,q3, xf1.y, xo1.y, c5, u5, h5)
    EPI(2, q1,q3, xf1.z, xo1.z, c6, u6, h6)
    EPI(3, q1,q3, xf1.w, xo1.w, c7, u7, h7)

    __syncthreads();   // all waves done reading h(t-1) from HB
    unsigned long long hpA = (unsigned long long)h0 | ((unsigned long long)h1<<16)
                           | ((unsigned long long)h2<<32) | ((unsigned long long)h3<<48);
    unsigned long long hpB = (unsigned long long)h4 | ((unsigned long long)h5<<16)
                           | ((unsigned long long)h6<<32) | ((unsigned long long)h7<<48);
    *(unsigned long long*)&HB[(w<<9) + (((lp>>1)<<4) + lr)*8 + ((lp&1)<<2)] = hpA;
    *(unsigned long long*)&HB[(w<<9) + (((2+(lp>>1))<<4) + lr)*8 + ((lp&1)<<2)] = hpB;
    unsigned long long* hdst =
      (unsigned long long*)(hs + ((size_t)(s*NB + bglob) << 8) + (w<<5) + (lp<<2));
    hdst[0] = hpA;
    hdst[4] = hpB;   // +16 shorts = +4 ull
    __syncthreads();   // h(t) ready in HB
  }
  *(float4*)(cstate + (size_t)bglob*256 + (w<<5) + (lp<<2)) = make_float4(c0,c1,c2,c3);
  *(float4*)(cstate + (size_t)bglob*256 + (w<<5) + 16 + (lp<<2)) = make_float4(c4,c5,c6,c7);
}

// ---- heads: logits = hs@actor_w.T + b ; values = hs@critic_w.T + b ----
__launch_bounds__(64,1) __global__ void k_proj(
    const unsigned short* __restrict__ hs, const float* __restrict__ actor_w,
    const float* __restrict__ actor_b, const float* __restrict__ critic_w,
    const float* __restrict__ critic_b, float* __restrict__ outL, float* __restrict__ outV){
  const int lane = threadIdx.x;
  const int m0 = blockIdx.x * 64;
  const int lr = lane & 15, lp = lane >> 4;
  f32x4 acc[4] = {};
  float part[4] = {0.f,0.f,0.f,0.f};
  #pragma unroll
  for (int kt=0;kt<8;kt++){
    BU bw;
    const float4* ap = (const float4*)(actor_w + (size_t)lr*256 + (kt<<5) + (lp<<3));
    float4 w0=ap[0], w1=ap[1];
    bw.us[0]=f2bf(w0.x); bw.us[1]=f2bf(w0.y); bw.us[2]=f2bf(w0.z); bw.us[3]=f2bf(w0.w);
    bw.us[4]=f2bf(w1.x); bw.us[5]=f2bf(w1.y); bw.us[6]=f2bf(w1.z); bw.us[7]=f2bf(w1.w);
    const float4* cp4 = (const float4*)(critic_w + (kt<<5) + (lp<<3));
    float4 cw0=cp4[0], cw1=cp4[1];
    #pragma unroll
    for (int mi=0;mi<4;mi++){
      BU hv; hv.u4 = *(const uint4*)(hs + ((size_t)(m0 + mi*16 + lr) << 8) + (kt<<5) + (lp<<3));
      acc[mi] = __builtin_amdgcn_mfma_f32_16x16x32_bf16(hv.v, bw.v, acc[mi], 0,0,0);
      part[mi] += bf2f(hv.us[0])*cw0.x + bf2f(hv.us[1])*cw0.y + bf2f(hv.us[2])*cw0.z + bf2f(hv.us[3])*cw0.w
                + bf2f(hv.us[4])*cw1.x + bf2f(hv.us[5])*cw1.y + bf2f(hv.us[6])*cw1.z + bf2f(hv.us[7])*cw1.w;
    }
  }
  const float ab = actor_b[lr];
  #pragma unroll
  for (int mi=0;mi<4;mi++){
    #pragma unroll
    for (int rr=0;rr<4;rr++)
      outL[(size_t)(m0 + mi*16 + lp*4 + rr)*16 + lr] = acc[mi][rr] + ab;
  }
  const float cb = critic_b[0];
  #pragma unroll
  for (int mi=0;mi<4;mi++){
    float v = part[mi];
    v += __shfl_xor(v, 16, 64);
    v += __shfl_xor(v, 32, 64);
    if (lp == 0) outV[m0 + mi*16 + lr] = v + cb;
  }
}

extern "C" void kernel_launch(void* const* d_in, const int* in_sizes, int n_in,
                              void* d_out, int out_size, void* d_ws, size_t ws_size,
                              hipStream_t stream) {
  (void)in_sizes; (void)n_in; (void)out_size;
  const float* input    = (const float*)d_in[0];
  const int*   lastact  = (const int*)d_in[1];
  const float* reward   = (const float*)d_in[2];
  const void*  done     = d_in[3];
  const float* hidden   = (const float*)d_in[4];
  const float* fc_w     = (const float*)d_in[5];
  const float* fc_b     = (const float*)d_in[6];
  const float* w_ih     = (const float*)d_in[7];
  const float* w_hh     = (const float*)d_in[8];
  const float* b_ih     = (const float*)d_in[9];
  const float* b_hh     = (const float*)d_in[10];
  const float* actor_w  = (const float*)d_in[11];
  const float* actor_b  = (const float*)d_in[12];
  const float* critic_w = (const float*)d_in[13];
  const float* critic_b = (const float*)d_in[14];
  float* outL = (float*)d_out;
  float* outV = outL + (size_t)NS*NA*NB;

  char* p = (char*)d_ws;
  unsigned*       hdr    = (unsigned*)p;                           // 256B
  unsigned char*  dmb    = (unsigned char*)(p + 1024);             // 131072
  unsigned short* wb     = (unsigned short*)(p + 132096);          // 196608
  float*          bsum   = (float*)(p + 328704);                   // 4096
  float*          cstate = (float*)(p + 332800);                   // 262144
  unsigned short* wpack  = (unsigned short*)(p + 594944);          // 524288
  const size_t fixed = 1119232;
  int CH = 128;   // xg (64MB) + hs (16MB) stay L3-resident per chunk
  while (CH > 4){
    size_t need = fixed + (size_t)CH*49152 + (size_t)CH*524288 + (size_t)CH*131072;
    if (need <= ws_size) break;
    CH >>= 1;
  }
  unsigned short* act = (unsigned short*)(p + fixed);
  unsigned short* xg  = (unsigned short*)(p + fixed + (size_t)CH*49152);
  unsigned short* hs  = (unsigned short*)(p + fixed + (size_t)CH*49152 + (size_t)CH*524288);

  hipMemsetAsync(d_ws, 0, 1024, stream);
  hipLaunchKernelGGL(k_detect, dim3(1), dim3(256), 0, stream, (const unsigned*)done, hdr);
  hipLaunchKernelGGL(k_norm, dim3(512), dim3(256), 0, stream,
                     (const unsigned char*)done, (const int*)done, hdr, dmb);
  hipLaunchKernelGGL(k_wbprep, dim3(4), dim3(256), 0, stream, w_ih, b_ih, b_hh, wb, bsum);
  hipLaunchKernelGGL(k_wprep2, dim3(128), dim3(256), 0, stream, w_hh, wpack);

  const int NC = NS / CH;
  for (int c = 0; c < NC; ++c){
    const int t0 = c * CH;
    hipLaunchKernelGGL(k_act, dim3(CH), dim3(256), 0, stream,
                       input, reward, lastact, fc_w, fc_b, act, t0*NB);
    hipLaunchKernelGGL(k_gemm, dim3(CH*2*8), dim3(256), 0, stream, act, wb, bsum, xg, CH*2);
    hipLaunchKernelGGL(k_main, dim3(16), dim3(512), 0, stream,
                       hidden, xg, dmb, wpack, hs, cstate, t0, CH);
    hipLaunchKernelGGL(k_proj, dim3(CH*4), dim3(64), 0, stream,
                       hs, actor_w, actor_b, critic_w, critic_b,
                       outL + (size_t)t0*NB*NA, outV + (size_t)t0*NB);
  }
}

// Round 12
// 2450.381 us; speedup vs baseline: 1.4914x; 1.3741x over previous
//
#include <hip/hip_runtime.h>
#include <hip/hip_bf16.h>

#define NS 512
#define NB 256
#define NA 16
#define NR_ 256

typedef short s16x8 __attribute__((ext_vector_type(8)));
typedef float f32x4 __attribute__((ext_vector_type(4)));

union BU { uint4 u4; unsigned short us[8]; s16x8 v; unsigned long long ull[2]; };

__device__ __forceinline__ float bf2f(unsigned short h){
  unsigned u = ((unsigned)h) << 16;
  return __builtin_bit_cast(float, u);
}
__device__ __forceinline__ unsigned short f2bf(float f){
  unsigned u = __builtin_bit_cast(unsigned, f);
  u += 0x7fffu + ((u >> 16) & 1u);
  return (unsigned short)(u >> 16);
}
__device__ __forceinline__ float fsig(float x){ return 1.f/(1.f+__expf(-x)); }
__device__ __forceinline__ float ftanh_(float x){ float e=__expf(2.f*x); return 1.f - 2.f/(e+1.f); }

// ---- detect done_flags dtype: u8-bool vs int32 (hdr[0]=1 -> byte format) ----
__global__ void k_detect(const unsigned* __restrict__ done, unsigned* __restrict__ hdr){
  unsigned any = 0;
  for (int i = threadIdx.x; i < 32768; i += 256) any |= (done[i] > 1u) ? 1u : 0u;
  if (__ballot(any)) { if ((threadIdx.x & 63) == 0) atomicOr(hdr, 1u); }
}

__global__ void k_norm(const unsigned char* __restrict__ d8, const int* __restrict__ d32,
                       const unsigned* __restrict__ hdr, unsigned char* __restrict__ dm){
  int i = blockIdx.x*256 + threadIdx.x;
  bool u8 = (hdr[0] & 1u) != 0;
  unsigned char v;
  if (u8) v = (d8[i] != 0) ? 1 : 0; else v = (d32[i] != 0) ? 1 : 0;
  dm[i] = v;
}

// ---- w_ih -> bf16 padded (1024 x 96), bsum = b_ih + b_hh ----
__global__ void k_wbprep(const float* __restrict__ w_ih, const float* __restrict__ b_ih,
                         const float* __restrict__ b_hh, unsigned short* __restrict__ wb,
                         float* __restrict__ bsum){
  const int g = blockIdx.x*256 + threadIdx.x;
  bsum[g] = b_ih[g] + b_hh[g];
  const float* src = w_ih + (size_t)g*81;
  unsigned short* dst = wb + (size_t)g*96;
  for (int k=0;k<81;k++) dst[k]=f2bf(src[k]);
  for (int k=81;k<96;k++) dst[k]=0;
}

// ---- pack w_hh: per (j, wave, kt, gate) frag, lane-linear ----
// Chunk {j, wv, fi=kt*4+g, lane(lr,lp)} holds w_hh[g*256+j*64+wv*16+lr][kt*32+lp*8..+7].
__global__ void k_wprep3(const float* __restrict__ w_hh, unsigned short* __restrict__ wpack3){
  const int G = blockIdx.x*256 + threadIdx.x;   // 0..32767
  const int lane = G & 63;
  const int fi = (G>>6) & 31;
  const int wv = (G>>11) & 3;
  const int j  = (G>>13) & 3;
  const int kt = fi >> 2, g = fi & 3;
  const int lr = lane & 15, lp = lane >> 4;
  const int grow = (g<<8) + (j<<6) + (wv<<4) + lr;
  const int kcol = (kt<<5) + (lp<<3);
  const float* src = w_hh + (size_t)grow*256 + kcol;
  float4 a = *(const float4*)src;
  float4 b = *(const float4*)(src+4);
  BU u;
  u.us[0]=f2bf(a.x); u.us[1]=f2bf(a.y); u.us[2]=f2bf(a.z); u.us[3]=f2bf(a.w);
  u.us[4]=f2bf(b.x); u.us[5]=f2bf(b.y); u.us[6]=f2bf(b.z); u.us[7]=f2bf(b.w);
  *(uint4*)(wpack3 + (size_t)G*8) = u.u4;
}

// ---- activations: act[r, 0:96] = [fc(x) | reward | onehot | pad] bf16 ----
__global__ void k_act(const float* __restrict__ input, const float* __restrict__ reward,
                      const int* __restrict__ lastact, const float* __restrict__ fc_w,
                      const float* __restrict__ fc_b, unsigned short* __restrict__ act, int n0){
  __shared__ float wf[1024];
  __shared__ float bfc[64];
  const int tid = threadIdx.x;
  for (int i=tid;i<1024;i+=256) wf[i]=fc_w[i];
  if (tid<64) bfc[tid]=fc_b[tid];
  __syncthreads();
  const int r = blockIdx.x*256 + tid;
  const int n = n0 + r;
  float in[16];
  const float4* ip = (const float4*)(input + (size_t)n*16);
  #pragma unroll
  for (int i=0;i<4;i++){ float4 v=ip[i]; in[4*i]=v.x; in[4*i+1]=v.y; in[4*i+2]=v.z; in[4*i+3]=v.w; }
  unsigned short o[96];
  const float4* wf4=(const float4*)wf;
  #pragma unroll
  for (int q=0;q<64;q++){
    float a=bfc[q];
    #pragma unroll
    for (int k4=0;k4<4;k4++){
      float4 wv=wf4[q*4+k4];
      a += in[4*k4]*wv.x + in[4*k4+1]*wv.y + in[4*k4+2]*wv.z + in[4*k4+3]*wv.w;
    }
    o[q]=f2bf(a);
  }
  o[64]=f2bf(reward[n]);
  const int la = lastact[n];
  #pragma unroll
  for (int k=0;k<16;k++) o[65+k] = (k==la) ? (unsigned short)0x3F80 : (unsigned short)0;
  #pragma unroll
  for (int k=81;k<96;k++) o[k]=0;
  uint4* dst=(uint4*)(act + (size_t)r*96);
  #pragma unroll
  for (int i=0;i<12;i++){
    BU b;
    #pragma unroll
    for (int jj=0;jj<8;jj++) b.us[jj]=o[i*8+jj];
    dst[i]=b.u4;
  }
}

// ---- Xg GEMM: xg[M,1024] = act[M,96] @ wb[1024,96]^T + bsum, bf16 out ----
__launch_bounds__(256,1) __global__ void k_gemm(
    const unsigned short* __restrict__ act, const unsigned short* __restrict__ wb,
    const float* __restrict__ bsum, unsigned short* __restrict__ xg, int mtiles){
  __shared__ __align__(16) unsigned short lA[128*104];
  __shared__ __align__(16) unsigned short lB[128*104];
  const int bm = blockIdx.x % mtiles;
  const int bn = blockIdx.x / mtiles;
  const int tid = threadIdx.x;
  {
    const int r = tid >> 1, sg = tid & 1;
    const uint4* sa = (const uint4*)(act + (size_t)(bm*128 + r)*96 + sg*48);
    const uint4* sb = (const uint4*)(wb  + (size_t)(bn*128 + r)*96 + sg*48);
    uint4* da = (uint4*)&lA[r*104 + sg*48];
    uint4* db = (uint4*)&lB[r*104 + sg*48];
    #pragma unroll
    for (int i=0;i<6;i++){ da[i]=sa[i]; db[i]=sb[i]; }
  }
  __syncthreads();
  const int wid = tid >> 6, lane = tid & 63;
  const int wm = wid >> 1, wn = wid & 1;
  const int lr = lane & 15, lp = lane >> 4;
  f32x4 acc[4][4] = {};
  #pragma unroll
  for (int kt=0;kt<3;kt++){
    s16x8 af[4], bf[4];
    #pragma unroll
    for (int mi=0;mi<4;mi++)
      af[mi] = *(const s16x8*)&lA[(wm*64 + mi*16 + lr)*104 + kt*32 + lp*8];
    #pragma unroll
    for (int ni=0;ni<4;ni++)
      bf[ni] = *(const s16x8*)&lB[(wn*64 + ni*16 + lr)*104 + kt*32 + lp*8];
    #pragma unroll
    for (int mi=0;mi<4;mi++){
      #pragma unroll
      for (int ni=0;ni<4;ni++)
        acc[mi][ni] = __builtin_amdgcn_mfma_f32_16x16x32_bf16(af[mi], bf[ni], acc[mi][ni], 0,0,0);
    }
  }
  #pragma unroll
  for (int ni=0;ni<4;ni++){
    const int col = bn*128 + wn*64 + ni*16 + lr;
    const float bias = bsum[col];
    #pragma unroll
    for (int mi=0;mi<4;mi++){
      const int row = bm*128 + wm*64 + mi*16 + lp*4;
      #pragma unroll
      for (int rr=0;rr<4;rr++)
        xg[((size_t)(row+rr)<<10) + col] = f2bf(acc[mi][ni][rr] + bias);
    }
  }
}

// ---- persistent LSTM core (R12): LDS lane-linear weights + R2 PROVEN exchange ----
// 64 WGs = 16 groups x 4 r-slices (gb=blk>>2, j=blk&3). 128KB weight slice
// LDS-resident (conflict-free). Exchange = R2 verbatim: h via relaxed-agent 8B
// atomic stores -> __syncthreads (vmcnt drain) -> flag store; consumers poll 4
// flags (bounded: wedge-proof) -> __syncthreads -> relaxed-agent 8B atomic loads.
__launch_bounds__(256,1) __global__ void k_main(
    const float* __restrict__ hidden, const unsigned short* __restrict__ xg,
    const unsigned char* __restrict__ dm, const unsigned short* __restrict__ wpack3,
    unsigned short* __restrict__ hs, float* __restrict__ cstate,
    unsigned* __restrict__ flags, int t0, int CH){
  __shared__ __align__(16) unsigned short LW[65536];  // 128KB weight slice
  const int tid = threadIdx.x;
  const int gb = blockIdx.x >> 2;   // batch group 0..15
  const int j  = blockIdx.x & 3;    // r-slice 0..3
  const int w = tid >> 6, lane = tid & 63;
  const int lr = lane & 15, lp = lane >> 4;
  const int b = (gb<<4) + lr;                         // batch row
  const int roff = (j<<6) + (w<<4) + (lp<<2);         // r base (4 rows/lane)

  // stage weights (pre-packed, linear copy)
  for (int it = tid; it < 8192; it += 256)
    *(uint4*)&LW[it*8] = *(const uint4*)(wpack3 + ((size_t)j<<16) + (size_t)it*8);

  float c0,c1,c2,c3;
  {
    const float* csrc = (t0 == 0) ? (hidden + 65536) : cstate;
    float4 cv = *(const float4*)(csrc + (size_t)b*256 + roff);
    c0=cv.x; c1=cv.y; c2=cv.z; c3=cv.w;
  }
  __syncthreads();

  for (int s = 0; s < CH; ++s){
    const int t = t0 + s;
    const bool dn = dm[t*NB + b] != 0;
    const unsigned short* xrow = xg + ((size_t)(s*NB + b) << 10) + roff;
    // xg prefetch issued before any wait
    ushort4 x0 = *(const ushort4*)(xrow);          // gate i
    ushort4 x1 = *(const ushort4*)(xrow + 256);    // gate f
    ushort4 x2 = *(const ushort4*)(xrow + 512);    // gate g
    ushort4 x3 = *(const ushort4*)(xrow + 768);    // gate o

    s16x8 bfr[8];
    if (t == 0){
      const float* hrow = hidden + (size_t)b*256;
      #pragma unroll
      for (int kt=0;kt<8;kt++){
        const float4* pp = (const float4*)(hrow + (kt<<5) + (lp<<3));
        float4 a=pp[0], bb=pp[1];
        BU u;
        u.us[0]=f2bf(a.x); u.us[1]=f2bf(a.y); u.us[2]=f2bf(a.z); u.us[3]=f2bf(a.w);
        u.us[4]=f2bf(bb.x); u.us[5]=f2bf(bb.y); u.us[6]=f2bf(bb.z); u.us[7]=f2bf(bb.w);
        if (dn) u.u4 = make_uint4(0,0,0,0);
        bfr[kt]=u.v;
      }
    } else {
      // R2-proven flag wait (bounded so a stall can never wedge the GPU)
      if (tid < 4){
        const unsigned tgt = (unsigned)t;
        int retry = 0;
        while (__hip_atomic_load(&flags[(gb<<2)+tid], __ATOMIC_RELAXED, __HIP_MEMORY_SCOPE_AGENT) < tgt){
          if (++retry > 2000000) break;
        }
      }
      __syncthreads();
      const int slot = (s == 0) ? CH : s;
      const unsigned long long* hq =
        (const unsigned long long*)(hs + ((size_t)(slot*NB + b) << 8) + lp*8);
      unsigned long long g[16];
      #pragma unroll
      for (int kt=0;kt<8;kt++){
        g[2*kt]   = __hip_atomic_load(hq + (size_t)kt*8,     __ATOMIC_RELAXED, __HIP_MEMORY_SCOPE_AGENT);
        g[2*kt+1] = __hip_atomic_load(hq + (size_t)kt*8 + 1, __ATOMIC_RELAXED, __HIP_MEMORY_SCOPE_AGENT);
      }
      #pragma unroll
      for (int kt=0;kt<8;kt++){
        BU u; u.ull[0]=g[2*kt]; u.ull[1]=g[2*kt+1];
        if (dn) u.u4 = make_uint4(0,0,0,0);
        bfr[kt]=u.v;
      }
    }

    f32x4 a0, a1, a2, a3;
    a0[0]=bf2f(x0.x); a0[1]=bf2f(x0.y); a0[2]=bf2f(x0.z); a0[3]=bf2f(x0.w);
    a1[0]=bf2f(x1.x); a1[1]=bf2f(x1.y); a1[2]=bf2f(x1.z); a1[3]=bf2f(x1.w);
    a2[0]=bf2f(x2.x); a2[1]=bf2f(x2.y); a2[2]=bf2f(x2.z); a2[3]=bf2f(x2.w);
    a3[0]=bf2f(x3.x); a3[1]=bf2f(x3.y); a3[2]=bf2f(x3.z); a3[3]=bf2f(x3.w);

    // 32 MFMAs: A from LDS (lane-linear, conflict-free), B = bfr
    #pragma unroll
    for (int kt=0;kt<8;kt++){
      s16x8 w0 = *(const s16x8*)&LW[(w<<14) + ((kt*4+0)<<9) + (lane<<3)];
      s16x8 w1 = *(const s16x8*)&LW[(w<<14) + ((kt*4+1)<<9) + (lane<<3)];
      s16x8 w2 = *(const s16x8*)&LW[(w<<14) + ((kt*4+2)<<9) + (lane<<3)];
      s16x8 w3 = *(const s16x8*)&LW[(w<<14) + ((kt*4+3)<<9) + (lane<<3)];
      a0 = __builtin_amdgcn_mfma_f32_16x16x32_bf16(w0, bfr[kt], a0, 0,0,0);
      a1 = __builtin_amdgcn_mfma_f32_16x16x32_bf16(w1, bfr[kt], a1, 0,0,0);
      a2 = __builtin_amdgcn_mfma_f32_16x16x32_bf16(w2, bfr[kt], a2, 0,0,0);
      a3 = __builtin_amdgcn_mfma_f32_16x16x32_bf16(w3, bfr[kt], a3, 0,0,0);
    }

    unsigned short hu[4];
    #pragma unroll
    for (int rr=0;rr<4;rr++){
      float cp = dn ? 0.f : ((rr==0)?c0:(rr==1)?c1:(rr==2)?c2:c3);
      float ii=fsig(a0[rr]), ff=fsig(a1[rr]), gg=ftanh_(a2[rr]), oo=fsig(a3[rr]);
      float cn = ff*cp + ii*gg;
      if (rr==0) c0=cn; else if (rr==1) c1=cn; else if (rr==2) c2=cn; else c3=cn;
      hu[rr] = f2bf(oo*ftanh_(cn));
    }
    unsigned long long hp = (unsigned long long)hu[0] | ((unsigned long long)hu[1]<<16)
                          | ((unsigned long long)hu[2]<<32) | ((unsigned long long)hu[3]<<48);
    // h slice -> coherence point (write-through agent atomic, R2-proven)
    __hip_atomic_store((unsigned long long*)(hs + ((size_t)((s+1)*NB + b) << 8) + roff),
                       hp, __ATOMIC_RELAXED, __HIP_MEMORY_SCOPE_AGENT);
    __syncthreads();  // drains vmcnt(0): h stores complete before flag post
    asm volatile("" ::: "memory");
    if (tid == 0)
      __hip_atomic_store(&flags[(gb<<2)+j], (unsigned)(t+1), __ATOMIC_RELAXED, __HIP_MEMORY_SCOPE_AGENT);
  }
  *(float4*)(cstate + (size_t)b*256 + roff) = make_float4(c0,c1,c2,c3);
}

// ---- heads: logits = hs@actor_w.T + b ; values = hs@critic_w.T + b ----
// hs slots 1..CH hold step outputs (offset 256 rows).
__launch_bounds__(64,1) __global__ void k_proj(
    const unsigned short* __restrict__ hs, const float* __restrict__ actor_w,
    const float* __restrict__ actor_b, const float* __restrict__ critic_w,
    const float* __restrict__ critic_b, float* __restrict__ outL, float* __restrict__ outV){
  const int lane = threadIdx.x;
  const int m0 = blockIdx.x * 64;
  const int lr = lane & 15, lp = lane >> 4;
  f32x4 acc[4] = {};
  float part[4] = {0.f,0.f,0.f,0.f};
  #pragma unroll
  for (int kt=0;kt<8;kt++){
    BU bw;
    const float4* ap = (const float4*)(actor_w + (size_t)lr*256 + (kt<<5) + (lp<<3));
    float4 w0=ap[0], w1=ap[1];
    bw.us[0]=f2bf(w0.x); bw.us[1]=f2bf(w0.y); bw.us[2]=f2bf(w0.z); bw.us[3]=f2bf(w0.w);
    bw.us[4]=f2bf(w1.x); bw.us[5]=f2bf(w1.y); bw.us[6]=f2bf(w1.z); bw.us[7]=f2bf(w1.w);
    const float4* cp4 = (const float4*)(critic_w + (kt<<5) + (lp<<3));
    float4 cw0=cp4[0], cw1=cp4[1];
    #pragma unroll
    for (int mi=0;mi<4;mi++){
      BU hv; hv.u4 = *(const uint4*)(hs + ((size_t)(256 + m0 + mi*16 + lr) << 8) + (kt<<5) + (lp<<3));
      acc[mi] = __builtin_amdgcn_mfma_f32_16x16x32_bf16(hv.v, bw.v, acc[mi], 0,0,0);
      part[mi] += bf2f(hv.us[0])*cw0.x + bf2f(hv.us[1])*cw0.y + bf2f(hv.us[2])*cw0.z + bf2f(hv.us[3])*cw0.w
                + bf2f(hv.us[4])*cw1.x + bf2f(hv.us[5])*cw1.y + bf2f(hv.us[6])*cw1.z + bf2f(hv.us[7])*cw1.w;
    }
  }
  const float ab = actor_b[lr];
  #pragma unroll
  for (int mi=0;mi<4;mi++){
    #pragma unroll
    for (int rr=0;rr<4;rr++)
      outL[(size_t)(m0 + mi*16 + lp*4 + rr)*16 + lr] = acc[mi][rr] + ab;
  }
  const float cb = critic_b[0];
  #pragma unroll
  for (int mi=0;mi<4;mi++){
    float v = part[mi];
    v += __shfl_xor(v, 16, 64);
    v += __shfl_xor(v, 32, 64);
    if (lp == 0) outV[m0 + mi*16 + lr] = v + cb;
  }
}

extern "C" void kernel_launch(void* const* d_in, const int* in_sizes, int n_in,
                              void* d_out, int out_size, void* d_ws, size_t ws_size,
                              hipStream_t stream) {
  (void)in_sizes; (void)n_in; (void)out_size;
  const float* input    = (const float*)d_in[0];
  const int*   lastact  = (const int*)d_in[1];
  const float* reward   = (const float*)d_in[2];
  const void*  done     = d_in[3];
  const float* hidden   = (const float*)d_in[4];
  const float* fc_w     = (const float*)d_in[5];
  const float* fc_b     = (const float*)d_in[6];
  const float* w_ih     = (const float*)d_in[7];
  const float* w_hh     = (const float*)d_in[8];
  const float* b_ih     = (const float*)d_in[9];
  const float* b_hh     = (const float*)d_in[10];
  const float* actor_w  = (const float*)d_in[11];
  const float* actor_b  = (const float*)d_in[12];
  const float* critic_w = (const float*)d_in[13];
  const float* critic_b = (const float*)d_in[14];
  float* outL = (float*)d_out;
  float* outV = outL + (size_t)NS*NA*NB;

  char* p = (char*)d_ws;
  unsigned*       hdr    = (unsigned*)p;                           // 0..256
  unsigned*       flags  = (unsigned*)(p + 256);                   // 64 u32
  unsigned char*  dmb    = (unsigned char*)(p + 1024);             // 131072
  unsigned short* wb     = (unsigned short*)(p + 132096);          // 196608
  float*          bsum   = (float*)(p + 328704);                   // 4096
  float*          cstate = (float*)(p + 332800);                   // 262144
  unsigned short* wpack3 = (unsigned short*)(p + 594944);          // 524288
  const size_t fixed = 1119232;
  int CH = 128;   // xg (67MB) + hs (17MB) L3-resident per chunk
  while (CH > 4){
    size_t need = fixed + (size_t)CH*49152 + (size_t)CH*524288 + ((size_t)CH+1)*131072;
    if (need <= ws_size) break;
    CH >>= 1;
  }
  unsigned short* act = (unsigned short*)(p + fixed);
  unsigned short* xg  = (unsigned short*)(p + fixed + (size_t)CH*49152);
  unsigned short* hs  = (unsigned short*)(p + fixed + (size_t)CH*49152 + (size_t)CH*524288);

  hipMemsetAsync(d_ws, 0, 1024, stream);   // hdr + flags (replay-safe)
  hipLaunchKernelGGL(k_detect, dim3(1), dim3(256), 0, stream, (const unsigned*)done, hdr);
  hipLaunchKernelGGL(k_norm, dim3(512), dim3(256), 0, stream,
                     (const unsigned char*)done, (const int*)done, hdr, dmb);
  hipLaunchKernelGGL(k_wbprep, dim3(4), dim3(256), 0, stream, w_ih, b_ih, b_hh, wb, bsum);
  hipLaunchKernelGGL(k_wprep3, dim3(128), dim3(256), 0, stream, w_hh, wpack3);

  const int NC = NS / CH;
  for (int c = 0; c < NC; ++c){
    const int t0 = c * CH;
    hipLaunchKernelGGL(k_act, dim3(CH), dim3(256), 0, stream,
                       input, reward, lastact, fc_w, fc_b, act, t0*NB);
    hipLaunchKernelGGL(k_gemm, dim3(CH*2*8), dim3(256), 0, stream, act, wb, bsum, xg, CH*2);
    hipLaunchKernelGGL(k_main, dim3(64), dim3(256), 0, stream,
                       hidden, xg, dmb, wpack3, hs, cstate, flags, t0, CH);
    hipLaunchKernelGGL(k_proj, dim3(CH*4), dim3(64), 0, stream,
                       hs, actor_w, actor_b, critic_w, critic_b,
                       outL + (size_t)t0*NB*NA, outV + (size_t)t0*NB);
  }
}